// Round 8
// baseline (548.565 us; speedup 1.0000x reference)
//
#include <hip/hip_runtime.h>

#define NROW  8192      // B*T
#define D_    1024
#define E_    2048
#define P2E_  4096
#define CD_   256
#define NC_   1024
#define BETA_ 0.25f
#define SPLITK 8

typedef __attribute__((ext_vector_type(8))) short short8;
typedef __attribute__((ext_vector_type(4))) float f32x4;

__device__ __forceinline__ ushort f2bf(float x) {
    union { float f; unsigned u; } v; v.f = x;
    unsigned r = (v.u + 0x7fffu + ((v.u >> 16) & 1u)) >> 16;
    return (ushort)r;
}
__device__ __forceinline__ float bf2f(ushort h) {
    union { unsigned u; float f; } v; v.u = ((unsigned)h) << 16;
    return v.f;
}
__device__ __forceinline__ void split2(float x, ushort& h, ushort& l) {
    h = f2bf(x);
    l = f2bf(x - bf2f(h));
}
__device__ __forceinline__ float gelu_tanh(float x) {
    float x3 = x * x * x;
    return 0.5f * x * (1.0f + tanhf(0.7978845608028654f * (x + 0.044715f * x3)));
}

// async global->LDS, 16B per lane
#define GLD16(gp, lp) __builtin_amdgcn_global_load_lds( \
    (const __attribute__((address_space(1))) void*)(gp), \
    (__attribute__((address_space(3))) void*)(lp), 16, 0, 0)

// ---------------------------------------------------------------------------
// Split-bf16 (3-term) MFMA GEMM.  C = A @ B^T = Ah.Bh + Ah.Bl + Al.Bh (fp32 acc)
// A: M x K row-major (hi/lo bf16) -> staged through LDS (16 KB, XOR-swizzled).
// B: N x K row-major (hi/lo bf16) -> L2-resident; loaded DIRECTLY global->VGPR
//    per-lane (16B frag chunks), register-double-buffered across the barrier.
// R7 post-mortem: old structure moved 128 KB/K-step through LDS (500 cy) vs
// 233 cy MFMA -> LDS-BW-bound at 47% MfmaUtil. B-direct cuts LDS to 48 KB
// (187 cy) -> MFMA-bound.
// Tile 128x128, BK=32, 256 threads = 4 waves (2x2), wave tile 64x64.
// Even/odd unrolled loop (ksteps always even) keeps B buffers statically
// indexed (rule #20). Schedule per K-step:
//   ds_read A frags -> barrier -> STAGE A(s+1) + load B(s+1) regs -> MFMA
//   (loads fly under MFMAs) -> barrier (vmcnt(0) drain)
// EPI 0: gelu(x + bias[n]) -> split -> Ph/Pl concat layout (GEMM1)
// EPI 1: partial fp32 -> outF[z*NROW + m][n]  (GEMM2, split-K via blockIdx.z)
// EPI 2: zeros -> outF tile; per-row argmin of (cn[n] - 2x) -> candv/candi
//        (GEMM3; reduction scratch aliases sAh/sAl)
// ---------------------------------------------------------------------------
template<int EPI>
__global__ __launch_bounds__(256, 3)
void gemm_bf16x3(const ushort* __restrict__ Ah, const ushort* __restrict__ Al,
                 const ushort* __restrict__ Bh, const ushort* __restrict__ Bl,
                 int K, int ksteps,
                 const float* __restrict__ bias,
                 float* __restrict__ outF,
                 ushort* __restrict__ oPh, ushort* __restrict__ oPl,
                 const float* __restrict__ cn,
                 float* __restrict__ candv, int* __restrict__ candi)
{
    __shared__ alignas(16) ushort sAh[4096], sAl[4096];   // 16 KB total
    const int t = threadIdx.x;
    const int l = t & 63;
    const int w = t >> 6;           // 0..3
    const int wr = w >> 1, wc = w & 1;

    // bijective XCD chunk swizzle (all grids have gridDim.x*gridDim.y % 8 == 0)
    const int nxy = gridDim.x * gridDim.y;
    const int id  = blockIdx.y * gridDim.x + blockIdx.x;
    const int swz = (id & 7) * (nxy >> 3) + (id >> 3);
    const int bx  = swz % gridDim.x;
    const int by  = swz / gridDim.x;

    const int bm = by * 128;
    const int bn = bx * 128;
    const int kstart = (EPI == 1) ? (int)blockIdx.z * (ksteps * 32) : 0;

    // ---- A staging (LDS): thread t covers row t>>2 (+64 second pass), 16B
    // slot t&3; global source pre-swizzled slot' = slot ^ ((row>>1)&3) ----
    const int srow = t >> 2;
    const int scol = ((t & 3) ^ ((t >> 3) & 3)) * 8;
    const ushort* gAh = Ah + (size_t)(bm + srow) * K + kstart + scol;
    const ushort* gAl = Al + (size_t)(bm + srow) * K + kstart + scol;
    const size_t rstep = (size_t)64 * K;
    const int lo0 = t * 8, lo1 = t * 8 + 2048;

    // ---- B direct: lane l covers col = bn + wc*64 + j*16 + (l&15),
    // k = kstart + s*32 + (l>>4)*8 (16B contiguous) ----
    const int kq = l >> 4, lr = l & 15;
    const ushort* pBh = Bh + (size_t)(bn + wc * 64 + lr) * K + kstart + kq * 8;
    const ushort* pBl = Bl + (size_t)(bn + wc * 64 + lr) * K + kstart + kq * 8;

    f32x4 acc[4][4];
#pragma unroll
    for (int i = 0; i < 4; i++)
#pragma unroll
        for (int j = 0; j < 4; j++) acc[i][j] = (f32x4)0.0f;

    // swizzled ds_read: row*32 + (kq ^ ((row>>1)&3))*8; (row>>1)&3 == (lr>>1)&3
    const int rsw = (kq ^ ((lr >> 1) & 3)) * 8;
    const int ar = (wr * 64 + lr) * 32 + rsw;

    short8 b0h[4], b0l[4], b1h[4], b1l[4];

#define STAGEA(koff) do { \
        GLD16(gAh + (koff), &sAh[lo0]); GLD16(gAh + (koff) + rstep, &sAh[lo1]); \
        GLD16(gAl + (koff), &sAl[lo0]); GLD16(gAl + (koff) + rstep, &sAl[lo1]); \
    } while (0)
#define LOADB(bh, bl, koff) do { \
        _Pragma("unroll") \
        for (int j = 0; j < 4; j++) { \
            bh[j] = *(const short8*)(pBh + (size_t)j * 16 * K + (koff)); \
            bl[j] = *(const short8*)(pBl + (size_t)j * 16 * K + (koff)); \
        } } while (0)
#define LDA() do { \
        _Pragma("unroll") \
        for (int i = 0; i < 4; i++) { \
            fah[i] = *(const short8*)&sAh[ar + i * 16 * 32]; \
            fal[i] = *(const short8*)&sAl[ar + i * 16 * 32]; \
        } } while (0)
#define MFMA3(bh, bl) do { \
        __builtin_amdgcn_s_setprio(1); \
        _Pragma("unroll") \
        for (int i = 0; i < 4; i++) \
            _Pragma("unroll") \
            for (int j = 0; j < 4; j++) { \
                acc[i][j] = __builtin_amdgcn_mfma_f32_16x16x32_bf16(fah[i], bh[j], acc[i][j], 0, 0, 0); \
                acc[i][j] = __builtin_amdgcn_mfma_f32_16x16x32_bf16(fah[i], bl[j], acc[i][j], 0, 0, 0); \
                acc[i][j] = __builtin_amdgcn_mfma_f32_16x16x32_bf16(fal[i], bh[j], acc[i][j], 0, 0, 0); \
            } \
        __builtin_amdgcn_s_setprio(0); \
    } while (0)

    LOADB(b0h, b0l, 0);       // B tile 0 -> regs
    STAGEA(0);                // A tile 0 -> LDS
    __syncthreads();          // vmcnt(0): A0 in LDS, B0 in regs

    for (int s = 0; s < ksteps; s += 2) {
        {   // ---- even step: consume A(s) from LDS + b0 ----
            short8 fah[4], fal[4];
            LDA();
            __syncthreads();                  // lgkm drained; A buffer free
            STAGEA((s + 1) * 32);             // s+1 < ksteps always (ksteps even)
            LOADB(b1h, b1l, (s + 1) * 32);    // flies under MFMAs
            MFMA3(b0h, b0l);
            __syncthreads();                  // vmcnt(0): A(s+1), B(s+1) ready
        }
        {   // ---- odd step: consume A(s+1) + b1 ----
            short8 fah[4], fal[4];
            LDA();
            __syncthreads();
            if (s + 2 < ksteps) {
                STAGEA((s + 2) * 32);
                LOADB(b0h, b0l, (s + 2) * 32);
            }
            MFMA3(b1h, b1l);
            __syncthreads();
        }
    }
#undef STAGEA
#undef LOADB
#undef LDA
#undef MFMA3

    // epilogue: C frag -> row = i*16 + kq*4 + r, col = j*16 + lr (m89 layout)
    if constexpr (EPI == 2) {
        float (*redv)[2] = (float(*)[2])sAh;   // 1 KB in dead sAh
        int   (*redi)[2] = (int(*)[2])sAl;
        float cnv[4];
#pragma unroll
        for (int j = 0; j < 4; j++) cnv[j] = cn[bn + wc * 64 + j * 16 + lr];
#pragma unroll
        for (int i = 0; i < 4; i++) {
            const int grow = bm + wr * 64 + i * 16 + kq * 4;
#pragma unroll
            for (int r = 0; r < 4; r++) {
                float bv = INFINITY; int bi = 0;
#pragma unroll
                for (int j = 0; j < 4; j++) {
                    float d = cnv[j] - 2.0f * acc[i][j][r];
                    int c = bn + wc * 64 + j * 16 + lr;
                    if (d < bv) { bv = d; bi = c; }
                }
#pragma unroll
                for (int m = 1; m < 16; m <<= 1) {
                    float ov = __shfl_xor(bv, m, 64);
                    int   oi = __shfl_xor(bi, m, 64);
                    if (ov < bv || (ov == bv && oi < bi)) { bv = ov; bi = oi; }
                }
                int rl = wr * 64 + i * 16 + kq * 4 + r;
                if (lr == 0) { redv[rl][wc] = bv; redi[rl][wc] = bi; }
                // zero the encodings tile (coalesced in 16-lane groups)
#pragma unroll
                for (int j = 0; j < 4; j++)
                    outF[(size_t)(grow + r) * NC_ + bn + wc * 64 + j * 16 + lr] = 0.0f;
            }
        }
        __syncthreads();
        if (t < 128) {
            float v0 = redv[t][0], v1 = redv[t][1];
            int   i0 = redi[t][0], i1 = redi[t][1];
            bool take1 = (v1 < v0) || (v1 == v0 && i1 < i0);
            candv[(size_t)(bm + t) * 8 + bx] = take1 ? v1 : v0;
            candi[(size_t)(bm + t) * 8 + bx] = take1 ? i1 : i0;
        }
        return;
    }

#pragma unroll
    for (int i = 0; i < 4; i++) {
        const int grow = bm + wr * 64 + i * 16 + kq * 4;
#pragma unroll
        for (int j = 0; j < 4; j++) {
            const int gcol = bn + wc * 64 + j * 16 + lr;
            f32x4 a = acc[i][j];
            if constexpr (EPI == 0) {
                const float bb = bias[gcol];
#pragma unroll
                for (int r = 0; r < 4; r++) {
                    int m = grow + r;
                    float x = gelu_tanh(a[r] + bb);
                    ushort h, lo; split2(x, h, lo);
                    int pr = (m < NROW) ? m : m - NROW;
                    int pc = ((m < NROW) ? 0 : E_) + gcol;
                    oPh[(size_t)pr * P2E_ + pc] = h;
                    oPl[(size_t)pr * P2E_ + pc] = lo;
                }
            } else if constexpr (EPI == 1) {
                float* o = outF + ((size_t)NROW * blockIdx.z + grow) * CD_ + gcol;
#pragma unroll
                for (int r = 0; r < 4; r++) o[(size_t)r * CD_] = a[r];
            }
        }
    }
}

// elementwise fp32 -> (hi,lo) bf16
__global__ void split_k(const float* __restrict__ in, ushort* __restrict__ oh,
                        ushort* __restrict__ ol, int n4)
{
    int i = blockIdx.x * blockDim.x + threadIdx.x;
    int stride = gridDim.x * blockDim.x;
    for (; i < n4; i += stride) {
        float4 v = ((const float4*)in)[i];
        ushort4 h, lo;
        split2(v.x, h.x, lo.x); split2(v.y, h.y, lo.y);
        split2(v.z, h.z, lo.z); split2(v.w, h.w, lo.w);
        ((ushort4*)oh)[i] = h;
        ((ushort4*)ol)[i] = lo;
    }
}

// transpose + split: in R x C fp32 -> out C x R (hi,lo) bf16
__global__ __launch_bounds__(1024)
void tsplit_k(const float* __restrict__ in, ushort* __restrict__ oh,
              ushort* __restrict__ ol, int R, int C)
{
    __shared__ float tile[32][33];
    int c0 = blockIdx.x * 32, r0 = blockIdx.y * 32;
    int tx = threadIdx.x, ty = threadIdx.y;
    tile[ty][tx] = in[(size_t)(r0 + ty) * C + c0 + tx];
    __syncthreads();
    float x = tile[tx][ty];
    ushort h, lo; split2(x, h, lo);
    size_t o = (size_t)(c0 + ty) * R + r0 + tx;
    oh[o] = h; ol[o] = lo;
}

// sum split-K partials + bias -> latent fp32, hi/lo bf16
__global__ __launch_bounds__(256)
void combine_k(const float* __restrict__ part, const float* __restrict__ bias,
               float* __restrict__ latent, ushort* __restrict__ lh,
               ushort* __restrict__ ll)
{
    int row = blockIdx.x, t = threadIdx.x;
    float x = bias[t];
#pragma unroll
    for (int z = 0; z < SPLITK; z++) x += part[((size_t)z * NROW + row) * CD_ + t];
    latent[(size_t)row * CD_ + t] = x;
    ushort h, lo; split2(x, h, lo);
    lh[(size_t)row * CD_ + t] = h;
    ll[(size_t)row * CD_ + t] = lo;
}

__global__ __launch_bounds__(256) void row_norms(const float* __restrict__ X,
                                                 float* __restrict__ out)
{
    __shared__ float s[256];
    int n = blockIdx.x, t = threadIdx.x;
    float v = X[(size_t)n * 256 + t];
    s[t] = v * v;
    __syncthreads();
    for (int st = 128; st > 0; st >>= 1) {
        if (t < st) s[t] += s[t + st];
        __syncthreads();
    }
    if (t == 0) out[n] = s[0];
}

__global__ void zero_hist(int* hist) { hist[threadIdx.x] = 0; }

// per-row finalize: combine 8 tile candidates -> bc; one-hot; quantize; loss parts
__global__ __launch_bounds__(256) void vq2_kernel(
    const float* __restrict__ latent, const float* __restrict__ cb,
    const float* __restrict__ candv, const int* __restrict__ candi,
    float* __restrict__ out_enc, float* __restrict__ out_q,
    float* __restrict__ out_idx, int* __restrict__ hist, float* __restrict__ lpart)
{
    __shared__ float sd[256];
    __shared__ int sbc;
    const int n = blockIdx.x, t = threadIdx.x;
    if (t == 0) {
        const float* cv = candv + (size_t)n * 8;
        const int*   ci = candi + (size_t)n * 8;
        float bv = cv[0]; int bi = ci[0];
#pragma unroll
        for (int k = 1; k < 8; k++) {
            float v = cv[k]; int x = ci[k];
            if (v < bv || (v == bv && x < bi)) { bv = v; bi = x; }
        }
        sbc = bi;
    }
    __syncthreads();
    const int bc = sbc;
    if (t == 0) out_enc[(size_t)n * NC_ + bc] = 1.0f;  // zeros by GEMM3 epilogue

    float lv = latent[(size_t)n * CD_ + t];
    float q  = cb[(size_t)bc * CD_ + t];
    out_q[(size_t)n * CD_ + t] = lv + (q - lv);
    float diff = q - lv;
    sd[t] = diff * diff;
    __syncthreads();
    for (int st = 128; st > 0; st >>= 1) {
        if (t < st) sd[t] += sd[t + st];
        __syncthreads();
    }
    if (t == 0) {
        lpart[n] = sd[0];
        atomicAdd(&hist[bc], 1);
        out_idx[n] = (float)bc;
    }
}

__global__ __launch_bounds__(1024) void finalize_kernel(
    const float* __restrict__ lpart, const int* __restrict__ hist,
    float* __restrict__ out_loss, float* __restrict__ out_perp)
{
    __shared__ float s[1024];
    int t = threadIdx.x;
    float x = 0.0f;
    for (int i = t; i < NROW; i += 1024) x += lpart[i];
    s[t] = x;
    __syncthreads();
    for (int st = 512; st > 0; st >>= 1) {
        if (t < st) s[t] += s[t + st];
        __syncthreads();
    }
    float total = s[0];
    __syncthreads();
    float p = (float)hist[t] * (1.0f / NROW);
    s[t] = p * logf(p + 1e-10f);
    __syncthreads();
    for (int st = 512; st > 0; st >>= 1) {
        if (t < st) s[t] += s[t + st];
        __syncthreads();
    }
    if (t == 0) {
        *out_loss = BETA_ * (total / (float)((size_t)NROW * CD_));
        *out_perp = expf(-s[0]);
    }
}

extern "C" void kernel_launch(void* const* d_in, const int* in_sizes, int n_in,
                              void* d_out, int out_size, void* d_ws, size_t ws_size,
                              hipStream_t stream)
{
    const float* states      = (const float*)d_in[0];
    const float* next_states = (const float*)d_in[1];
    const float* W_s         = (const float*)d_in[2];
    const float* b_s         = (const float*)d_in[3];
    const float* W_p         = (const float*)d_in[4];
    const float* b_p         = (const float*)d_in[5];
    const float* codebook    = (const float*)d_in[6];

    float* out      = (float*)d_out;
    float* out_q    = out;
    float* out_loss = out + (size_t)NROW * CD_;
    float* out_perp = out_loss + 1;
    float* out_enc  = out_perp + 1;                  // zeroed by GEMM3 epi, 1-set by vq2
    float* out_idx  = out_enc + (size_t)NROW * NC_;

    char* ws = (char*)d_ws;
    size_t off = 0;
    auto alloc = [&](size_t bytes) { void* p = ws + off; off += (bytes + 255) & ~255ull; return p; };

    ushort* A1h  = (ushort*)alloc((size_t)2 * NROW * D_ * 2);   // 32 MiB
    ushort* A1l  = (ushort*)alloc((size_t)2 * NROW * D_ * 2);   // 32 MiB
    ushort* WsTh = (ushort*)alloc((size_t)E_ * D_ * 2);
    ushort* WsTl = (ushort*)alloc((size_t)E_ * D_ * 2);
    ushort* WpTh = (ushort*)alloc((size_t)CD_ * P2E_ * 2);
    ushort* WpTl = (ushort*)alloc((size_t)CD_ * P2E_ * 2);
    ushort* cbh  = (ushort*)alloc((size_t)NC_ * CD_ * 2);
    ushort* cbl  = (ushort*)alloc((size_t)NC_ * CD_ * 2);
    ushort* Ph   = (ushort*)alloc((size_t)NROW * P2E_ * 2);     // 64 MiB
    ushort* Pl   = (ushort*)alloc((size_t)NROW * P2E_ * 2);
    ushort* lath = (ushort*)alloc((size_t)NROW * CD_ * 2);
    ushort* latl = (ushort*)alloc((size_t)NROW * CD_ * 2);
    float*  cbn  = (float*)alloc(NC_ * 4);
    int*    hist = (int*)alloc(NC_ * 4);
    float*  lpart= (float*)alloc(NROW * 4);
    float*  candv= (float*)alloc((size_t)NROW * 8 * 4);
    int*    candi= (int*)alloc((size_t)NROW * 8 * 4);
    // aliases over dead regions (A1/WsT dead after GEMM1):
    float* lat_part = (float*)A1h;    // SPLITK*8192*256*4 = 64 MiB over A1h+A1l
    float* latent   = (float*)WsTh;   // 8 MiB over WsTh+WsTl

    // --- conversions ---
    {
        int n4 = NROW * D_ / 4;
        split_k<<<2048, 256, 0, stream>>>(states, A1h, A1l, n4);
        split_k<<<2048, 256, 0, stream>>>(next_states, A1h + (size_t)NROW * D_,
                                          A1l + (size_t)NROW * D_, n4);
    }
    tsplit_k<<<dim3(E_ / 32, D_ / 32), dim3(32, 32), 0, stream>>>(W_s, WsTh, WsTl, D_, E_);
    tsplit_k<<<dim3(CD_ / 32, P2E_ / 32), dim3(32, 32), 0, stream>>>(W_p, WpTh, WpTl, P2E_, CD_);
    split_k<<<256, 256, 0, stream>>>(codebook, cbh, cbl, NC_ * CD_ / 4);
    row_norms<<<NC_, 256, 0, stream>>>(codebook, cbn);

    // --- GEMM1: P = gelu([states;next_states] @ W_s + b_s), concat layout, split hi/lo ---
    gemm_bf16x3<0><<<dim3(E_ / 128, 2 * NROW / 128), 256, 0, stream>>>(
        A1h, A1l, WsTh, WsTl, D_, D_ / 32, b_s, nullptr, Ph, Pl, nullptr, nullptr, nullptr);

    // --- GEMM2: latent partials (split-K = 8) ---
    gemm_bf16x3<1><<<dim3(CD_ / 128, NROW / 128, SPLITK), 256, 0, stream>>>(
        Ph, Pl, WpTh, WpTl, P2E_, P2E_ / 32 / SPLITK, nullptr, lat_part, nullptr, nullptr,
        nullptr, nullptr, nullptr);

    // --- combine: bias + fp32 latent + hi/lo ---
    combine_k<<<NROW, 256, 0, stream>>>(lat_part, b_p, latent, lath, latl);

    // --- GEMM3: fused distance + per-tile argmin; zeros encodings region ---
    gemm_bf16x3<2><<<dim3(NC_ / 128, NROW / 128), 256, 0, stream>>>(
        lath, latl, cbh, cbl, CD_, CD_ / 32, nullptr, out_enc, nullptr, nullptr,
        cbn, candv, candi);

    // --- VQ finalize + scalars ---
    zero_hist<<<1, NC_, 0, stream>>>(hist);
    vq2_kernel<<<NROW, 256, 0, stream>>>(latent, codebook, candv, candi,
                                         out_enc, out_q, out_idx, hist, lpart);
    finalize_kernel<<<1, 1024, 0, stream>>>(lpart, hist, out_loss, out_perp);
}

// Round 9
// 378.047 us; speedup vs baseline: 1.4511x; 1.4511x over previous
//
#include <hip/hip_runtime.h>

#define NROW  8192      // B*T
#define D_    1024
#define E_    2048
#define P2E_  4096
#define CD_   256
#define NC_   1024
#define BETA_ 0.25f
#define SPLITK 8

typedef __attribute__((ext_vector_type(8))) short short8;
typedef __attribute__((ext_vector_type(4))) float f32x4;

__device__ __forceinline__ ushort f2bf(float x) {
    union { float f; unsigned u; } v; v.f = x;
    unsigned r = (v.u + 0x7fffu + ((v.u >> 16) & 1u)) >> 16;
    return (ushort)r;
}
__device__ __forceinline__ float bf2f(ushort h) {
    union { unsigned u; float f; } v; v.u = ((unsigned)h) << 16;
    return v.f;
}
__device__ __forceinline__ void split2(float x, ushort& h, ushort& l) {
    h = f2bf(x);
    l = f2bf(x - bf2f(h));
}
__device__ __forceinline__ float gelu_tanh(float x) {
    float x3 = x * x * x;
    return 0.5f * x * (1.0f + tanhf(0.7978845608028654f * (x + 0.044715f * x3)));
}

// async global->LDS, 16B per lane
#define GLD16(gp, lp) __builtin_amdgcn_global_load_lds( \
    (const __attribute__((address_space(1))) void*)(gp), \
    (__attribute__((address_space(3))) void*)(lp), 16, 0, 0)

// ---------------------------------------------------------------------------
// Split-bf16 (3-term) MFMA GEMM.  C = A @ B^T = Ah.Bh + Ah.Bl + Al.Bh (fp32 acc)
// A: M x K row-major (hi/lo bf16), B: N x K row-major (hi/lo bf16).
// R7 post-mortem: 64x64 wave tiles -> LDS-BW cap 47% (measured 47%).
// NEW geometry: block 256x128, 256 thr = 4 waves (2M x 2N), wave tile 128x64.
// LDS/wave/K-step = (128+64)*128B + 12KB staging share = 36 KB -> cap ~81%.
// A double-buffered in LDS (A-frags are ds_read per-i INSIDE the MFMA loop,
// overlapping MFMAs; 2nd buffer removes write-under-read race). B (8 frag
// reads) read up-front, single-buffered. All staging via global_load_lds
// (R8 showed per-lane B-direct loses). LDS 80 KB -> 2 blocks/CU = reg limit.
// Schedule per K-step (R5-verified 2-barrier):
//   read B frags -> barrier -> STAGE A(s+1)->buf^1, B(s+1) -> MFMA loop
//   (per-i A ds_reads + 12 MFMAs, staging flies under) -> barrier (vmcnt 0)
// LDS XOR swizzle on 16B slots (both-sides: pre-swizzled global src + ds_read).
// EPI 0: gelu(x + bias[n]) -> split -> Ph/Pl concat layout (GEMM1)
// EPI 1: partial fp32 -> outF[z*NROW + m][n]  (GEMM2, split-K via blockIdx.z)
// EPI 2: zeros -> outF tile; per-row argmin of (cn[n] - 2x) -> candv/candi
//        (GEMM3; reduction scratch aliases sBh/sBl)
// ---------------------------------------------------------------------------
template<int EPI>
__global__ __launch_bounds__(256, 2)
void gemm_bf16x3(const ushort* __restrict__ Ah, const ushort* __restrict__ Al,
                 const ushort* __restrict__ Bh, const ushort* __restrict__ Bl,
                 int K, int ksteps,
                 const float* __restrict__ bias,
                 float* __restrict__ outF,
                 ushort* __restrict__ oPh, ushort* __restrict__ oPl,
                 const float* __restrict__ cn,
                 float* __restrict__ candv, int* __restrict__ candi)
{
    __shared__ alignas(16) ushort sAh2[16384], sAl2[16384];  // 2 bufs x 16 KB each
    __shared__ alignas(16) ushort sBh[4096], sBl[4096];      // 8 KB each
    const int t = threadIdx.x;
    const int l = t & 63;
    const int w = t >> 6;           // 0..3
    const int wr = w >> 1, wc = w & 1;

    // bijective XCD chunk swizzle (all grids have gridDim.x*gridDim.y % 8 == 0)
    const int nxy = gridDim.x * gridDim.y;
    const int id  = blockIdx.y * gridDim.x + blockIdx.x;
    const int swz = (id & 7) * (nxy >> 3) + (id >> 3);
    const int bx  = swz % gridDim.x;
    const int by  = swz / gridDim.x;

    const int bm = by * 256;
    const int bn = bx * 128;
    const int kstart = (EPI == 1) ? (int)blockIdx.z * (ksteps * 32) : 0;

    // staging: thread t covers row t>>2 (+64p), 16B slot t&3; global source
    // pre-swizzled: slot' = slot ^ ((row>>1)&3) = (t&3) ^ ((t>>3)&3)
    const int srow = t >> 2;
    const int scol = ((t & 3) ^ ((t >> 3) & 3)) * 8;
    const ushort* gAh = Ah + (size_t)(bm + srow) * K + kstart + scol;
    const ushort* gAl = Al + (size_t)(bm + srow) * K + kstart + scol;
    const ushort* gBh = Bh + (size_t)(bn + srow) * K + kstart + scol;
    const ushort* gBl = Bl + (size_t)(bn + srow) * K + kstart + scol;
    const size_t rstep = (size_t)64 * K;
    const int d8 = t * 8;

    f32x4 acc[8][4];
#pragma unroll
    for (int i = 0; i < 8; i++)
#pragma unroll
        for (int j = 0; j < 4; j++) acc[i][j] = (f32x4)0.0f;

    // swizzled ds_read: row*32 + (kq ^ ((row>>1)&3))*8; (row>>1)&3 == (lr>>1)&3
    const int kq = l >> 4, lr = l & 15;
    const int rsw = (kq ^ ((lr >> 1) & 3)) * 8;
    const int ar0 = (wr * 128 + lr) * 32 + rsw;    // + i*512 + buf*8192
    const int br0 = (wc * 64 + lr) * 32 + rsw;     // + j*512

#define STAGEA(buf, koff) do { \
        _Pragma("unroll") \
        for (int p = 0; p < 4; p++) { \
            GLD16(gAh + (koff) + p * rstep, &sAh2[(buf) * 8192 + d8 + p * 2048]); \
            GLD16(gAl + (koff) + p * rstep, &sAl2[(buf) * 8192 + d8 + p * 2048]); \
        } } while (0)
#define STAGEB(koff) do { \
        _Pragma("unroll") \
        for (int p = 0; p < 2; p++) { \
            GLD16(gBh + (koff) + p * rstep, &sBh[d8 + p * 2048]); \
            GLD16(gBl + (koff) + p * rstep, &sBl[d8 + p * 2048]); \
        } } while (0)

    STAGEA(0, 0);
    STAGEB(0);
    __syncthreads();          // vmcnt(0) drain: tile 0 resident

    int cur = 0;
    for (int s = 0; s < ksteps; ++s) {
        short8 fbh[4], fbl[4];
#pragma unroll
        for (int j = 0; j < 4; j++) {
            fbh[j] = *(const short8*)&sBh[br0 + j * 512];
            fbl[j] = *(const short8*)&sBl[br0 + j * 512];
        }
        __syncthreads();      // B reads done (lgkm drained); sBh/sBl free

        if (s + 1 < ksteps) { // next tile's loads fly under the MFMA loop
            STAGEA(cur ^ 1, (s + 1) * 32);
            STAGEB((s + 1) * 32);
        }

        const int ab = cur * 8192;
        __builtin_amdgcn_s_setprio(1);
#pragma unroll
        for (int i = 0; i < 8; i++) {
            short8 fah = *(const short8*)&sAh2[ab + ar0 + i * 512];
            short8 fal = *(const short8*)&sAl2[ab + ar0 + i * 512];
#pragma unroll
            for (int j = 0; j < 4; j++) {
                acc[i][j] = __builtin_amdgcn_mfma_f32_16x16x32_bf16(fah, fbh[j], acc[i][j], 0, 0, 0);
                acc[i][j] = __builtin_amdgcn_mfma_f32_16x16x32_bf16(fah, fbl[j], acc[i][j], 0, 0, 0);
                acc[i][j] = __builtin_amdgcn_mfma_f32_16x16x32_bf16(fal, fbh[j], acc[i][j], 0, 0, 0);
            }
        }
        __builtin_amdgcn_s_setprio(0);
        __syncthreads();      // vmcnt(0): next tile resident; A reads drained
        cur ^= 1;
    }
#undef STAGEA
#undef STAGEB

    // epilogue: C frag -> row = i*16 + kq*4 + r, col = j*16 + lr (m89 layout)
    if constexpr (EPI == 2) {
        float (*redv)[2] = (float(*)[2])sBh;   // 2 KB in dead sBh
        int   (*redi)[2] = (int(*)[2])sBl;
        float cnv[4];
#pragma unroll
        for (int j = 0; j < 4; j++) cnv[j] = cn[bn + wc * 64 + j * 16 + lr];
#pragma unroll
        for (int i = 0; i < 8; i++) {
            const int grow = bm + wr * 128 + i * 16 + kq * 4;
#pragma unroll
            for (int r = 0; r < 4; r++) {
                float bv = INFINITY; int bi = 0;
#pragma unroll
                for (int j = 0; j < 4; j++) {
                    float d = cnv[j] - 2.0f * acc[i][j][r];
                    int c = bn + wc * 64 + j * 16 + lr;
                    if (d < bv) { bv = d; bi = c; }
                }
#pragma unroll
                for (int m = 1; m < 16; m <<= 1) {
                    float ov = __shfl_xor(bv, m, 64);
                    int   oi = __shfl_xor(bi, m, 64);
                    if (ov < bv || (ov == bv && oi < bi)) { bv = ov; bi = oi; }
                }
                int rl = wr * 128 + i * 16 + kq * 4 + r;
                if (lr == 0) { redv[rl][wc] = bv; redi[rl][wc] = bi; }
                // zero the encodings tile (coalesced in 16-lane groups)
#pragma unroll
                for (int j = 0; j < 4; j++)
                    outF[(size_t)(grow + r) * NC_ + bn + wc * 64 + j * 16 + lr] = 0.0f;
            }
        }
        __syncthreads();
        {   // all 256 threads: one row each
            float v0 = redv[t][0], v1 = redv[t][1];
            int   i0 = redi[t][0], i1 = redi[t][1];
            bool take1 = (v1 < v0) || (v1 == v0 && i1 < i0);
            candv[(size_t)(bm + t) * 8 + bx] = take1 ? v1 : v0;
            candi[(size_t)(bm + t) * 8 + bx] = take1 ? i1 : i0;
        }
        return;
    }

#pragma unroll
    for (int i = 0; i < 8; i++) {
        const int grow = bm + wr * 128 + i * 16 + kq * 4;
#pragma unroll
        for (int j = 0; j < 4; j++) {
            const int gcol = bn + wc * 64 + j * 16 + lr;
            f32x4 a = acc[i][j];
            if constexpr (EPI == 0) {
                const float bb = bias[gcol];
#pragma unroll
                for (int r = 0; r < 4; r++) {
                    int m = grow + r;
                    float x = gelu_tanh(a[r] + bb);
                    ushort h, lo; split2(x, h, lo);
                    int pr = (m < NROW) ? m : m - NROW;
                    int pc = ((m < NROW) ? 0 : E_) + gcol;
                    oPh[(size_t)pr * P2E_ + pc] = h;
                    oPl[(size_t)pr * P2E_ + pc] = lo;
                }
            } else if constexpr (EPI == 1) {
                float* o = outF + ((size_t)NROW * blockIdx.z + grow) * CD_ + gcol;
#pragma unroll
                for (int r = 0; r < 4; r++) o[(size_t)r * CD_] = a[r];
            }
        }
    }
}

// elementwise fp32 -> (hi,lo) bf16
__global__ void split_k(const float* __restrict__ in, ushort* __restrict__ oh,
                        ushort* __restrict__ ol, int n4)
{
    int i = blockIdx.x * blockDim.x + threadIdx.x;
    int stride = gridDim.x * blockDim.x;
    for (; i < n4; i += stride) {
        float4 v = ((const float4*)in)[i];
        ushort4 h, lo;
        split2(v.x, h.x, lo.x); split2(v.y, h.y, lo.y);
        split2(v.z, h.z, lo.z); split2(v.w, h.w, lo.w);
        ((ushort4*)oh)[i] = h;
        ((ushort4*)ol)[i] = lo;
    }
}

// transpose + split: in R x C fp32 -> out C x R (hi,lo) bf16
__global__ __launch_bounds__(1024)
void tsplit_k(const float* __restrict__ in, ushort* __restrict__ oh,
              ushort* __restrict__ ol, int R, int C)
{
    __shared__ float tile[32][33];
    int c0 = blockIdx.x * 32, r0 = blockIdx.y * 32;
    int tx = threadIdx.x, ty = threadIdx.y;
    tile[ty][tx] = in[(size_t)(r0 + ty) * C + c0 + tx];
    __syncthreads();
    float x = tile[tx][ty];
    ushort h, lo; split2(x, h, lo);
    size_t o = (size_t)(c0 + ty) * R + r0 + tx;
    oh[o] = h; ol[o] = lo;
}

// sum split-K partials + bias -> latent fp32, hi/lo bf16
__global__ __launch_bounds__(256)
void combine_k(const float* __restrict__ part, const float* __restrict__ bias,
               float* __restrict__ latent, ushort* __restrict__ lh,
               ushort* __restrict__ ll)
{
    int row = blockIdx.x, t = threadIdx.x;
    float x = bias[t];
#pragma unroll
    for (int z = 0; z < SPLITK; z++) x += part[((size_t)z * NROW + row) * CD_ + t];
    latent[(size_t)row * CD_ + t] = x;
    ushort h, lo; split2(x, h, lo);
    lh[(size_t)row * CD_ + t] = h;
    ll[(size_t)row * CD_ + t] = lo;
}

__global__ __launch_bounds__(256) void row_norms(const float* __restrict__ X,
                                                 float* __restrict__ out)
{
    __shared__ float s[256];
    int n = blockIdx.x, t = threadIdx.x;
    float v = X[(size_t)n * 256 + t];
    s[t] = v * v;
    __syncthreads();
    for (int st = 128; st > 0; st >>= 1) {
        if (t < st) s[t] += s[t + st];
        __syncthreads();
    }
    if (t == 0) out[n] = s[0];
}

__global__ void zero_hist(int* hist) { hist[threadIdx.x] = 0; }

// per-row finalize: combine 8 tile candidates -> bc; one-hot; quantize; loss parts
__global__ __launch_bounds__(256) void vq2_kernel(
    const float* __restrict__ latent, const float* __restrict__ cb,
    const float* __restrict__ candv, const int* __restrict__ candi,
    float* __restrict__ out_enc, float* __restrict__ out_q,
    float* __restrict__ out_idx, int* __restrict__ hist, float* __restrict__ lpart)
{
    __shared__ float sd[256];
    __shared__ int sbc;
    const int n = blockIdx.x, t = threadIdx.x;
    if (t == 0) {
        const float* cv = candv + (size_t)n * 8;
        const int*   ci = candi + (size_t)n * 8;
        float bv = cv[0]; int bi = ci[0];
#pragma unroll
        for (int k = 1; k < 8; k++) {
            float v = cv[k]; int x = ci[k];
            if (v < bv || (v == bv && x < bi)) { bv = v; bi = x; }
        }
        sbc = bi;
    }
    __syncthreads();
    const int bc = sbc;
    if (t == 0) out_enc[(size_t)n * NC_ + bc] = 1.0f;  // zeros by GEMM3 epilogue

    float lv = latent[(size_t)n * CD_ + t];
    float q  = cb[(size_t)bc * CD_ + t];
    out_q[(size_t)n * CD_ + t] = lv + (q - lv);
    float diff = q - lv;
    sd[t] = diff * diff;
    __syncthreads();
    for (int st = 128; st > 0; st >>= 1) {
        if (t < st) sd[t] += sd[t + st];
        __syncthreads();
    }
    if (t == 0) {
        lpart[n] = sd[0];
        atomicAdd(&hist[bc], 1);
        out_idx[n] = (float)bc;
    }
}

__global__ __launch_bounds__(1024) void finalize_kernel(
    const float* __restrict__ lpart, const int* __restrict__ hist,
    float* __restrict__ out_loss, float* __restrict__ out_perp)
{
    __shared__ float s[1024];
    int t = threadIdx.x;
    float x = 0.0f;
    for (int i = t; i < NROW; i += 1024) x += lpart[i];
    s[t] = x;
    __syncthreads();
    for (int st = 512; st > 0; st >>= 1) {
        if (t < st) s[t] += s[t + st];
        __syncthreads();
    }
    float total = s[0];
    __syncthreads();
    float p = (float)hist[t] * (1.0f / NROW);
    s[t] = p * logf(p + 1e-10f);
    __syncthreads();
    for (int st = 512; st > 0; st >>= 1) {
        if (t < st) s[t] += s[t + st];
        __syncthreads();
    }
    if (t == 0) {
        *out_loss = BETA_ * (total / (float)((size_t)NROW * CD_));
        *out_perp = expf(-s[0]);
    }
}

extern "C" void kernel_launch(void* const* d_in, const int* in_sizes, int n_in,
                              void* d_out, int out_size, void* d_ws, size_t ws_size,
                              hipStream_t stream)
{
    const float* states      = (const float*)d_in[0];
    const float* next_states = (const float*)d_in[1];
    const float* W_s         = (const float*)d_in[2];
    const float* b_s         = (const float*)d_in[3];
    const float* W_p         = (const float*)d_in[4];
    const float* b_p         = (const float*)d_in[5];
    const float* codebook    = (const float*)d_in[6];

    float* out      = (float*)d_out;
    float* out_q    = out;
    float* out_loss = out + (size_t)NROW * CD_;
    float* out_perp = out_loss + 1;
    float* out_enc  = out_perp + 1;                  // zeroed by GEMM3 epi, 1-set by vq2
    float* out_idx  = out_enc + (size_t)NROW * NC_;

    char* ws = (char*)d_ws;
    size_t off = 0;
    auto alloc = [&](size_t bytes) { void* p = ws + off; off += (bytes + 255) & ~255ull; return p; };

    ushort* A1h  = (ushort*)alloc((size_t)2 * NROW * D_ * 2);   // 32 MiB
    ushort* A1l  = (ushort*)alloc((size_t)2 * NROW * D_ * 2);   // 32 MiB
    ushort* WsTh = (ushort*)alloc((size_t)E_ * D_ * 2);
    ushort* WsTl = (ushort*)alloc((size_t)E_ * D_ * 2);
    ushort* WpTh = (ushort*)alloc((size_t)CD_ * P2E_ * 2);
    ushort* WpTl = (ushort*)alloc((size_t)CD_ * P2E_ * 2);
    ushort* cbh  = (ushort*)alloc((size_t)NC_ * CD_ * 2);
    ushort* cbl  = (ushort*)alloc((size_t)NC_ * CD_ * 2);
    ushort* Ph   = (ushort*)alloc((size_t)NROW * P2E_ * 2);     // 64 MiB
    ushort* Pl   = (ushort*)alloc((size_t)NROW * P2E_ * 2);
    ushort* lath = (ushort*)alloc((size_t)NROW * CD_ * 2);
    ushort* latl = (ushort*)alloc((size_t)NROW * CD_ * 2);
    float*  cbn  = (float*)alloc(NC_ * 4);
    int*    hist = (int*)alloc(NC_ * 4);
    float*  lpart= (float*)alloc(NROW * 4);
    float*  candv= (float*)alloc((size_t)NROW * 8 * 4);
    int*    candi= (int*)alloc((size_t)NROW * 8 * 4);
    // aliases over dead regions (A1/WsT dead after GEMM1):
    float* lat_part = (float*)A1h;    // SPLITK*8192*256*4 = 64 MiB over A1h+A1l
    float* latent   = (float*)WsTh;   // 8 MiB over WsTh+WsTl

    // --- conversions ---
    {
        int n4 = NROW * D_ / 4;
        split_k<<<2048, 256, 0, stream>>>(states, A1h, A1l, n4);
        split_k<<<2048, 256, 0, stream>>>(next_states, A1h + (size_t)NROW * D_,
                                          A1l + (size_t)NROW * D_, n4);
    }
    tsplit_k<<<dim3(E_ / 32, D_ / 32), dim3(32, 32), 0, stream>>>(W_s, WsTh, WsTl, D_, E_);
    tsplit_k<<<dim3(CD_ / 32, P2E_ / 32), dim3(32, 32), 0, stream>>>(W_p, WpTh, WpTl, P2E_, CD_);
    split_k<<<256, 256, 0, stream>>>(codebook, cbh, cbl, NC_ * CD_ / 4);
    row_norms<<<NC_, 256, 0, stream>>>(codebook, cbn);

    // --- GEMM1: P = gelu([states;next_states] @ W_s + b_s), concat layout, split hi/lo ---
    gemm_bf16x3<0><<<dim3(E_ / 128, 2 * NROW / 256), 256, 0, stream>>>(
        A1h, A1l, WsTh, WsTl, D_, D_ / 32, b_s, nullptr, Ph, Pl, nullptr, nullptr, nullptr);

    // --- GEMM2: latent partials (split-K = 8) ---
    gemm_bf16x3<1><<<dim3(CD_ / 128, NROW / 256, SPLITK), 256, 0, stream>>>(
        Ph, Pl, WpTh, WpTl, P2E_, P2E_ / 32 / SPLITK, nullptr, lat_part, nullptr, nullptr,
        nullptr, nullptr, nullptr);

    // --- combine: bias + fp32 latent + hi/lo ---
    combine_k<<<NROW, 256, 0, stream>>>(lat_part, b_p, latent, lath, latl);

    // --- GEMM3: fused distance + per-tile argmin; zeros encodings region ---
    gemm_bf16x3<2><<<dim3(NC_ / 128, NROW / 256), 256, 0, stream>>>(
        lath, latl, cbh, cbl, CD_, CD_ / 32, nullptr, out_enc, nullptr, nullptr,
        cbn, candv, candi);

    // --- VQ finalize + scalars ---
    zero_hist<<<1, NC_, 0, stream>>>(hist);
    vq2_kernel<<<NROW, 256, 0, stream>>>(latent, codebook, candv, candi,
                                         out_enc, out_q, out_idx, hist, lpart);
    finalize_kernel<<<1, 1024, 0, stream>>>(lpart, hist, out_loss, out_perp);
}

// Round 10
// 368.823 us; speedup vs baseline: 1.4873x; 1.0250x over previous
//
#include <hip/hip_runtime.h>

#define NROW  8192      // B*T
#define D_    1024
#define E_    2048
#define P2E_  4096
#define CD_   256
#define NC_   1024
#define BETA_ 0.25f
#define SPLITK 4

typedef __attribute__((ext_vector_type(8))) short short8;
typedef __attribute__((ext_vector_type(4))) float f32x4;

__device__ __forceinline__ ushort f2bf(float x) {
    union { float f; unsigned u; } v; v.f = x;
    unsigned r = (v.u + 0x7fffu + ((v.u >> 16) & 1u)) >> 16;
    return (ushort)r;
}
__device__ __forceinline__ float bf2f(ushort h) {
    union { unsigned u; float f; } v; v.u = ((unsigned)h) << 16;
    return v.f;
}
__device__ __forceinline__ void split2(float x, ushort& h, ushort& l) {
    h = f2bf(x);
    l = f2bf(x - bf2f(h));
}
__device__ __forceinline__ float gelu_tanh(float x) {
    float x3 = x * x * x;
    return 0.5f * x * (1.0f + tanhf(0.7978845608028654f * (x + 0.044715f * x3)));
}

// async global->LDS, 16B per lane
#define GLD16(gp, lp) __builtin_amdgcn_global_load_lds( \
    (const __attribute__((address_space(1))) void*)(gp), \
    (__attribute__((address_space(3))) void*)(lp), 16, 0, 0)

// ---------------------------------------------------------------------------
// Split-bf16 (3-term) MFMA GEMM.  C = A @ B^T = Ah.Bh + Ah.Bl + Al.Bh (fp32 acc)
// A: M x K row-major (hi/lo bf16), B: N x K row-major (hi/lo bf16).
// Tile 128x128, BK=32, 256 threads = 4 waves (2x2), wave tile 64x64.
// R9 post-mortem: MfmaUtil invariant ~45% across all 2-barrier-drain variants
// -> latency-bound on the per-step vmcnt(0) drain, NOT LDS/MFMA/HBM. Fix = T4:
// COUNTED vmcnt, loads never drained in-loop. 2-buffer LDS (64 KB, 2 blk/CU).
//   prologue: STG(buf0,t0); STG(buf1,t1)            (8 VMEM/wave per tile)
//   iter s:  s_waitcnt vmcnt(8)   // tile s landed; tile s+1 stays in flight
//            s_barrier            // all waves' tile-s staging visible
//            ds_read B frags + per-i A frags -> 48 MFMA (compiler lgkmcnt)
//            s_barrier            // buf cur reads done (all data consumed)
//            STG(buf cur, tile s+2)   // refill freed buffer; flies 2 steps
// Raw barriers via mem-clobbered asm (no auto vmcnt(0)); plain C++ ds_reads so
// the compiler tracks dataflow (rule-18 trap avoided; no sched_barrier).
// LDS XOR swizzle on 16B slots (both-sides: pre-swizzled global src + ds_read).
// EPI 0: gelu(x + bias[n]) -> split -> Ph/Pl concat layout (GEMM1)
// EPI 1: partial fp32 -> outF[z*NROW + m][n]  (GEMM2, split-K via blockIdx.z)
// EPI 2: dists (rn[m] - 2x) + cn[n] -> outF[m*NC_+n]  (GEMM3, R3-style)
// ---------------------------------------------------------------------------
template<int EPI>
__global__ __launch_bounds__(256, 2)
void gemm_bf16x3(const ushort* __restrict__ Ah, const ushort* __restrict__ Al,
                 const ushort* __restrict__ Bh, const ushort* __restrict__ Bl,
                 int K, int ksteps,
                 const float* __restrict__ bias,
                 float* __restrict__ outF,
                 ushort* __restrict__ oPh, ushort* __restrict__ oPl,
                 const float* __restrict__ rn, const float* __restrict__ cn)
{
    __shared__ alignas(16) ushort sAh[2][4096], sAl[2][4096], sBh[2][4096], sBl[2][4096];
    const int t = threadIdx.x;
    const int l = t & 63;
    const int w = t >> 6;
    const int wr = w >> 1, wc = w & 1;

    // bijective XCD chunk swizzle (all grids have gridDim.x*gridDim.y % 8 == 0)
    const int nxy = gridDim.x * gridDim.y;
    const int id  = blockIdx.y * gridDim.x + blockIdx.x;
    const int swz = (id & 7) * (nxy >> 3) + (id >> 3);
    const int bx  = swz % gridDim.x;
    const int by  = swz / gridDim.x;

    const int bm = by * 128;
    const int bn = bx * 128;
    const int kstart = (EPI == 1) ? (int)blockIdx.z * (ksteps * 32) : 0;

    // staging: 2 passes x 16B per thread per matrix tile; LDS dest linear.
    // global source pre-swizzled: slot' = slot ^ ((row>>1)&3), row = t>>2 (+64)
    const int srow = t >> 2;
    const int scol = ((t & 3) ^ ((t >> 3) & 3)) * 8;
    const ushort* gAh = Ah + (size_t)(bm + srow) * K + kstart + scol;
    const ushort* gAl = Al + (size_t)(bm + srow) * K + kstart + scol;
    const ushort* gBh = Bh + (size_t)(bn + srow) * K + kstart + scol;
    const ushort* gBl = Bl + (size_t)(bn + srow) * K + kstart + scol;
    const size_t rstep = (size_t)64 * K;
    const int lo0 = t * 8, lo1 = t * 8 + 2048;

    f32x4 acc[4][4];
#pragma unroll
    for (int i = 0; i < 4; i++)
#pragma unroll
        for (int j = 0; j < 4; j++) acc[i][j] = (f32x4)0.0f;

    // swizzled ds_read: row*32 + (kq ^ ((row>>1)&3))*8; (row>>1)&3 == (lr>>1)&3
    const int kq = l >> 4, lr = l & 15;
    const int rsw = (kq ^ ((lr >> 1) & 3)) * 8;
    const int ar = (wr * 64 + lr) * 32 + rsw;   // + i*512
    const int br = (wc * 64 + lr) * 32 + rsw;   // + j*512

#define STG(buf, koff) do { \
        GLD16(gAh + (koff), &sAh[buf][lo0]); GLD16(gAh + (koff) + rstep, &sAh[buf][lo1]); \
        GLD16(gAl + (koff), &sAl[buf][lo0]); GLD16(gAl + (koff) + rstep, &sAl[buf][lo1]); \
        GLD16(gBh + (koff), &sBh[buf][lo0]); GLD16(gBh + (koff) + rstep, &sBh[buf][lo1]); \
        GLD16(gBl + (koff), &sBl[buf][lo0]); GLD16(gBl + (koff) + rstep, &sBl[buf][lo1]); \
    } while (0)

    STG(0, 0);                // tile 0 -> buf 0   (8 VMEM/wave)
    STG(1, 32);               // tile 1 -> buf 1   (ksteps >= 2 always)

    for (int s = 0; s < ksteps; ++s) {
        const int cur = s & 1;
        // tile s landed; tile s+1 (8 loads) stays in flight across the step
        if (s + 1 < ksteps) asm volatile("s_waitcnt vmcnt(8)" ::: "memory");
        else                asm volatile("s_waitcnt vmcnt(0)" ::: "memory");
        asm volatile("s_barrier" ::: "memory");

        short8 fbh[4], fbl[4];
#pragma unroll
        for (int j = 0; j < 4; j++) {
            fbh[j] = *(const short8*)&sBh[cur][br + j * 512];
            fbl[j] = *(const short8*)&sBl[cur][br + j * 512];
        }
        __builtin_amdgcn_s_setprio(1);
#pragma unroll
        for (int i = 0; i < 4; i++) {
            short8 fah = *(const short8*)&sAh[cur][ar + i * 512];
            short8 fal = *(const short8*)&sAl[cur][ar + i * 512];
#pragma unroll
            for (int j = 0; j < 4; j++) {
                acc[i][j] = __builtin_amdgcn_mfma_f32_16x16x32_bf16(fah, fbh[j], acc[i][j], 0, 0, 0);
                acc[i][j] = __builtin_amdgcn_mfma_f32_16x16x32_bf16(fah, fbl[j], acc[i][j], 0, 0, 0);
                acc[i][j] = __builtin_amdgcn_mfma_f32_16x16x32_bf16(fal, fbh[j], acc[i][j], 0, 0, 0);
            }
        }
        __builtin_amdgcn_s_setprio(0);
        // all reads of buf cur consumed (lgkm drained by MFMA operand waits)
        asm volatile("s_barrier" ::: "memory");
        if (s + 2 < ksteps) STG(cur, (s + 2) * 32);   // refill freed buffer
    }
#undef STG

    // epilogue: C frag -> row = i*16 + kq*4 + r, col = j*16 + lr (m89 layout)
#pragma unroll
    for (int i = 0; i < 4; i++) {
        const int grow = bm + wr * 64 + i * 16 + kq * 4;
#pragma unroll
        for (int j = 0; j < 4; j++) {
            const int gcol = bn + wc * 64 + j * 16 + lr;
            f32x4 a = acc[i][j];
            if constexpr (EPI == 0) {
                const float bb = bias[gcol];
#pragma unroll
                for (int r = 0; r < 4; r++) {
                    int m = grow + r;
                    float x = gelu_tanh(a[r] + bb);
                    ushort h, lo; split2(x, h, lo);
                    int pr = (m < NROW) ? m : m - NROW;
                    int pc = ((m < NROW) ? 0 : E_) + gcol;
                    oPh[(size_t)pr * P2E_ + pc] = h;
                    oPl[(size_t)pr * P2E_ + pc] = lo;
                }
            } else if constexpr (EPI == 1) {
                float* o = outF + ((size_t)NROW * blockIdx.z + grow) * CD_ + gcol;
#pragma unroll
                for (int r = 0; r < 4; r++) o[(size_t)r * CD_] = a[r];
            } else {
#pragma unroll
                for (int r = 0; r < 4; r++) {
                    int m = grow + r;
                    outF[(size_t)m * NC_ + gcol] = (rn[m] - 2.0f * a[r]) + cn[gcol];
                }
            }
        }
    }
}

// elementwise fp32 -> (hi,lo) bf16
__global__ void split_k(const float* __restrict__ in, ushort* __restrict__ oh,
                        ushort* __restrict__ ol, int n4)
{
    int i = blockIdx.x * blockDim.x + threadIdx.x;
    int stride = gridDim.x * blockDim.x;
    for (; i < n4; i += stride) {
        float4 v = ((const float4*)in)[i];
        ushort4 h, lo;
        split2(v.x, h.x, lo.x); split2(v.y, h.y, lo.y);
        split2(v.z, h.z, lo.z); split2(v.w, h.w, lo.w);
        ((ushort4*)oh)[i] = h;
        ((ushort4*)ol)[i] = lo;
    }
}

// transpose + split: in R x C fp32 -> out C x R (hi,lo) bf16
__global__ __launch_bounds__(1024)
void tsplit_k(const float* __restrict__ in, ushort* __restrict__ oh,
              ushort* __restrict__ ol, int R, int C)
{
    __shared__ float tile[32][33];
    int c0 = blockIdx.x * 32, r0 = blockIdx.y * 32;
    int tx = threadIdx.x, ty = threadIdx.y;
    tile[ty][tx] = in[(size_t)(r0 + ty) * C + c0 + tx];
    __syncthreads();
    float x = tile[tx][ty];
    ushort h, lo; split2(x, h, lo);
    size_t o = (size_t)(c0 + ty) * R + r0 + tx;
    oh[o] = h; ol[o] = lo;
}

// sum split-K partials + bias -> latent fp32, hi/lo bf16, row norms
__global__ __launch_bounds__(256)
void combine_k(const float* __restrict__ part, const float* __restrict__ bias,
               float* __restrict__ latent, ushort* __restrict__ lh,
               ushort* __restrict__ ll, float* __restrict__ rown)
{
    __shared__ float red[256];
    int row = blockIdx.x, t = threadIdx.x;
    float x = bias[t];
#pragma unroll
    for (int z = 0; z < SPLITK; z++) x += part[((size_t)z * NROW + row) * CD_ + t];
    latent[(size_t)row * CD_ + t] = x;
    ushort h, lo; split2(x, h, lo);
    lh[(size_t)row * CD_ + t] = h;
    ll[(size_t)row * CD_ + t] = lo;
    red[t] = x * x;
    __syncthreads();
    for (int st = 128; st > 0; st >>= 1) { if (t < st) red[t] += red[t + st]; __syncthreads(); }
    if (t == 0) rown[row] = red[0];
}

__global__ __launch_bounds__(256) void row_norms(const float* __restrict__ X,
                                                 float* __restrict__ out)
{
    __shared__ float s[256];
    int n = blockIdx.x, t = threadIdx.x;
    float v = X[(size_t)n * 256 + t];
    s[t] = v * v;
    __syncthreads();
    for (int st = 128; st > 0; st >>= 1) {
        if (t < st) s[t] += s[t + st];
        __syncthreads();
    }
    if (t == 0) out[n] = s[0];
}

__global__ void zero_hist(int* hist) { hist[threadIdx.x] = 0; }

// One block per latent row. dists_enc holds dists on entry; overwritten with one-hot.
__global__ __launch_bounds__(256) void vq_kernel(
    const float* __restrict__ latent, const float* __restrict__ cb,
    float* __restrict__ dists_enc, float* __restrict__ out_q,
    float* __restrict__ out_idx, int* __restrict__ hist, float* __restrict__ lpart)
{
    __shared__ float sd[256];
    __shared__ int   si[256];
    const int n = blockIdx.x, tid = threadIdx.x;
    float* drow = dists_enc + (size_t)n * NC_;

    float best = INFINITY;
    int bidx = 0;
#pragma unroll
    for (int j = 0; j < NC_ / 256; j++) {
        int c = tid + j * 256;
        float d = drow[c];
        if (d < best) { best = d; bidx = c; }
    }
    sd[tid] = best; si[tid] = bidx;
    __syncthreads();
    for (int st = 128; st > 0; st >>= 1) {
        if (tid < st) {
            float d2 = sd[tid + st]; int i2 = si[tid + st];
            if (d2 < sd[tid] || (d2 == sd[tid] && i2 < si[tid])) { sd[tid] = d2; si[tid] = i2; }
        }
        __syncthreads();
    }
    const int bc = si[0];

#pragma unroll
    for (int j = 0; j < NC_ / 256; j++) {
        int c = tid + j * 256;
        drow[c] = (c == bc) ? 1.0f : 0.0f;
    }

    float lv = latent[(size_t)n * CD_ + tid];
    float q  = cb[(size_t)bc * CD_ + tid];
    out_q[(size_t)n * CD_ + tid] = lv + (q - lv);
    float diff = q - lv;
    __syncthreads();
    sd[tid] = diff * diff;
    __syncthreads();
    for (int st = 128; st > 0; st >>= 1) {
        if (tid < st) sd[tid] += sd[tid + st];
        __syncthreads();
    }
    if (tid == 0) {
        lpart[n] = sd[0];
        atomicAdd(&hist[bc], 1);
        out_idx[n] = (float)bc;
    }
}

__global__ __launch_bounds__(1024) void finalize_kernel(
    const float* __restrict__ lpart, const int* __restrict__ hist,
    float* __restrict__ out_loss, float* __restrict__ out_perp)
{
    __shared__ float s[1024];
    int t = threadIdx.x;
    float x = 0.0f;
    for (int i = t; i < NROW; i += 1024) x += lpart[i];
    s[t] = x;
    __syncthreads();
    for (int st = 512; st > 0; st >>= 1) {
        if (t < st) s[t] += s[t + st];
        __syncthreads();
    }
    float total = s[0];
    __syncthreads();
    float p = (float)hist[t] * (1.0f / NROW);
    s[t] = p * logf(p + 1e-10f);
    __syncthreads();
    for (int st = 512; st > 0; st >>= 1) {
        if (t < st) s[t] += s[t + st];
        __syncthreads();
    }
    if (t == 0) {
        *out_loss = BETA_ * (total / (float)((size_t)NROW * CD_));
        *out_perp = expf(-s[0]);
    }
}

extern "C" void kernel_launch(void* const* d_in, const int* in_sizes, int n_in,
                              void* d_out, int out_size, void* d_ws, size_t ws_size,
                              hipStream_t stream)
{
    const float* states      = (const float*)d_in[0];
    const float* next_states = (const float*)d_in[1];
    const float* W_s         = (const float*)d_in[2];
    const float* b_s         = (const float*)d_in[3];
    const float* W_p         = (const float*)d_in[4];
    const float* b_p         = (const float*)d_in[5];
    const float* codebook    = (const float*)d_in[6];

    float* out      = (float*)d_out;
    float* out_q    = out;
    float* out_loss = out + (size_t)NROW * CD_;
    float* out_perp = out_loss + 1;
    float* out_enc  = out_perp + 1;                  // dists scratch -> one-hot
    float* out_idx  = out_enc + (size_t)NROW * NC_;

    char* ws = (char*)d_ws;
    size_t off = 0;
    auto alloc = [&](size_t bytes) { void* p = ws + off; off += (bytes + 255) & ~255ull; return p; };

    ushort* A1h  = (ushort*)alloc((size_t)2 * NROW * D_ * 2);   // 32 MiB
    ushort* A1l  = (ushort*)alloc((size_t)2 * NROW * D_ * 2);   // 32 MiB
    ushort* WsTh = (ushort*)alloc((size_t)E_ * D_ * 2);
    ushort* WsTl = (ushort*)alloc((size_t)E_ * D_ * 2);
    ushort* WpTh = (ushort*)alloc((size_t)CD_ * P2E_ * 2);
    ushort* WpTl = (ushort*)alloc((size_t)CD_ * P2E_ * 2);
    ushort* cbh  = (ushort*)alloc((size_t)NC_ * CD_ * 2);
    ushort* cbl  = (ushort*)alloc((size_t)NC_ * CD_ * 2);
    ushort* Ph   = (ushort*)alloc((size_t)NROW * P2E_ * 2);     // 64 MiB
    ushort* Pl   = (ushort*)alloc((size_t)NROW * P2E_ * 2);
    ushort* lath = (ushort*)alloc((size_t)NROW * CD_ * 2);
    ushort* latl = (ushort*)alloc((size_t)NROW * CD_ * 2);
    float*  rown = (float*)alloc(NROW * 4);
    float*  cbn  = (float*)alloc(NC_ * 4);
    int*    hist = (int*)alloc(NC_ * 4);
    float*  lpart= (float*)alloc(NROW * 4);
    // aliases over dead regions (A1/WsT dead after GEMM1):
    float* lat_part = (float*)A1h;    // SPLITK*8192*256*4 = 32 MiB in A1h
    float* latent   = (float*)WsTh;   // 8 MiB over WsTh+WsTl

    // --- conversions ---
    {
        int n4 = NROW * D_ / 4;
        split_k<<<2048, 256, 0, stream>>>(states, A1h, A1l, n4);
        split_k<<<2048, 256, 0, stream>>>(next_states, A1h + (size_t)NROW * D_,
                                          A1l + (size_t)NROW * D_, n4);
    }
    tsplit_k<<<dim3(E_ / 32, D_ / 32), dim3(32, 32), 0, stream>>>(W_s, WsTh, WsTl, D_, E_);
    tsplit_k<<<dim3(CD_ / 32, P2E_ / 32), dim3(32, 32), 0, stream>>>(W_p, WpTh, WpTl, P2E_, CD_);
    split_k<<<256, 256, 0, stream>>>(codebook, cbh, cbl, NC_ * CD_ / 4);
    row_norms<<<NC_, 256, 0, stream>>>(codebook, cbn);

    // --- GEMM1: P = gelu([states;next_states] @ W_s + b_s), concat layout, split hi/lo ---
    gemm_bf16x3<0><<<dim3(E_ / 128, 2 * NROW / 128), 256, 0, stream>>>(
        A1h, A1l, WsTh, WsTl, D_, D_ / 32, b_s, nullptr, Ph, Pl, nullptr, nullptr);

    // --- GEMM2: latent partials (split-K = 4) ---
    gemm_bf16x3<1><<<dim3(CD_ / 128, NROW / 128, SPLITK), 256, 0, stream>>>(
        Ph, Pl, WpTh, WpTl, P2E_, P2E_ / 32 / SPLITK, nullptr, lat_part, nullptr, nullptr,
        nullptr, nullptr);

    // --- combine: bias + fp32 latent + hi/lo + row norms ---
    combine_k<<<NROW, 256, 0, stream>>>(lat_part, b_p, latent, lath, latl, rown);

    // --- GEMM3: dists into encodings region (R3-style) ---
    gemm_bf16x3<2><<<dim3(NC_ / 128, NROW / 128), 256, 0, stream>>>(
        lath, latl, cbh, cbl, CD_, CD_ / 32, nullptr, out_enc, nullptr, nullptr,
        rown, cbn);

    // --- VQ: argmin, one-hot (in place), quantize_st, loss partials, histogram ---
    zero_hist<<<1, NC_, 0, stream>>>(hist);
    vq_kernel<<<NROW, 256, 0, stream>>>(latent, codebook, out_enc, out_q, out_idx, hist, lpart);

    // --- scalars ---
    finalize_kernel<<<1, 1024, 0, stream>>>(lpart, hist, out_loss, out_perp);
}

// Round 11
// 341.307 us; speedup vs baseline: 1.6072x; 1.0806x over previous
//
#include <hip/hip_runtime.h>

#define NROW  8192      // B*T
#define D_    1024
#define E_    2048
#define P2E_  4096
#define CD_   256
#define NC_   1024
#define BETA_ 0.25f
#define SPLITK 4

typedef __attribute__((ext_vector_type(8))) short short8;
typedef __attribute__((ext_vector_type(4))) float f32x4;

__device__ __forceinline__ ushort f2bf(float x) {
    union { float f; unsigned u; } v; v.f = x;
    unsigned r = (v.u + 0x7fffu + ((v.u >> 16) & 1u)) >> 16;
    return (ushort)r;
}
__device__ __forceinline__ float bf2f(ushort h) {
    union { unsigned u; float f; } v; v.u = ((unsigned)h) << 16;
    return v.f;
}
__device__ __forceinline__ void split2(float x, ushort& h, ushort& l) {
    h = f2bf(x);
    l = f2bf(x - bf2f(h));
}
__device__ __forceinline__ float gelu_tanh(float x) {
    float x3 = x * x * x;
    return 0.5f * x * (1.0f + tanhf(0.7978845608028654f * (x + 0.044715f * x3)));
}

// async global->LDS, 16B per lane
#define GLD16(gp, lp) __builtin_amdgcn_global_load_lds( \
    (const __attribute__((address_space(1))) void*)(gp), \
    (__attribute__((address_space(3))) void*)(lp), 16, 0, 0)

// ---------------------------------------------------------------------------
// Split-bf16 (3-term) MFMA GEMM.  C = A @ B^T = Ah.Bh + Ah.Bl + Al.Bh (fp32 acc)
// A: M x K row-major (hi/lo bf16), B: N x K row-major (hi/lo bf16).
// Tile 128x128, BK=32, 256 threads = 4 waves (2x2), each wave 64x64 (4x4 frags).
// MEASURED-OPTIMAL structure (R3/R5: GEMM1 207us, MfmaUtil 47%, conflicts 0;
// every structural variant tried in R4/R6/R7/R8/R9/R10 regressed):
//   iter s: ds_read frags -> barrier -> STAGE(next tile) -> MFMA (loads fly
//   under MFMAs) -> barrier (vmcnt(0) drain)
// Single 32KB LDS buffer keeps >=3 blocks/CU resident (the controlling
// variable: <=2 blocks/CU always measured 38-44% MfmaUtil, >=3 gives 47%).
// LDS XOR swizzle on 16B slots (both-sides: pre-swizzled global src + ds_read).
// EPI 0: gelu(x + bias[n]) -> split -> Ph/Pl with concat layout (GEMM1)
// EPI 1: partial fp32 -> outF[z*NROW + m][n]  (GEMM2, split-K via blockIdx.z)
// EPI 2: dists (rn[m] - 2x) + cn[n] -> outF[m*NC_+n]  (GEMM3)
// ---------------------------------------------------------------------------
template<int EPI>
__global__ __launch_bounds__(256)
void gemm_bf16x3(const ushort* __restrict__ Ah, const ushort* __restrict__ Al,
                 const ushort* __restrict__ Bh, const ushort* __restrict__ Bl,
                 int K, int ksteps,
                 const float* __restrict__ bias,
                 float* __restrict__ outF,
                 ushort* __restrict__ oPh, ushort* __restrict__ oPl,
                 const float* __restrict__ rn, const float* __restrict__ cn)
{
    __shared__ alignas(16) ushort sAh[4096], sAl[4096], sBh[4096], sBl[4096];
    const int t = threadIdx.x;
    const int l = t & 63;
    const int w = t >> 6;
    const int wr = w >> 1, wc = w & 1;

    // bijective XCD chunk swizzle (all grids have gridDim.x*gridDim.y % 8 == 0)
    const int nxy = gridDim.x * gridDim.y;
    const int id  = blockIdx.y * gridDim.x + blockIdx.x;
    const int swz = (id & 7) * (nxy >> 3) + (id >> 3);
    const int bx  = swz % gridDim.x;
    const int by  = swz / gridDim.x;

    const int bm = by * 128;
    const int bn = bx * 128;
    const int kstart = (EPI == 1) ? (int)blockIdx.z * (ksteps * 32) : 0;

    // staging: 2 passes x 16B per thread per matrix tile; LDS dest linear (t*16B).
    // global source pre-swizzled: slot' = slot ^ ((row>>1)&3), row = t>>2 (+64)
    const int srow = t >> 2;                       // 0..63
    const int scol = ((t & 3) ^ ((t >> 3) & 3)) * 8;
    const ushort* gAh = Ah + (size_t)(bm + srow) * K + kstart + scol;
    const ushort* gAl = Al + (size_t)(bm + srow) * K + kstart + scol;
    const ushort* gBh = Bh + (size_t)(bn + srow) * K + kstart + scol;
    const ushort* gBl = Bl + (size_t)(bn + srow) * K + kstart + scol;
    const size_t rstep = (size_t)64 * K;
    const int lo0 = t * 8, lo1 = t * 8 + 2048;

    f32x4 acc[4][4];
#pragma unroll
    for (int i = 0; i < 4; i++)
#pragma unroll
        for (int j = 0; j < 4; j++) acc[i][j] = (f32x4)0.0f;

    // swizzled ds_read address: row = wr*64 + i*16 + (l&15); slot = (l>>4) ^ ((row>>1)&3)
    const int rsw = ((l >> 4) ^ (((l & 15) >> 1) & 3)) * 8;
    const int ar = (wr * 64 + (l & 15)) * 32 + rsw;
    const int br = (wc * 64 + (l & 15)) * 32 + rsw;

#define STAGE8() do { \
        GLD16(gAh, &sAh[lo0]); GLD16(gAh + rstep, &sAh[lo1]); \
        GLD16(gAl, &sAl[lo0]); GLD16(gAl + rstep, &sAl[lo1]); \
        GLD16(gBh, &sBh[lo0]); GLD16(gBh + rstep, &sBh[lo1]); \
        GLD16(gBl, &sBl[lo0]); GLD16(gBl + rstep, &sBl[lo1]); \
    } while (0)

    STAGE8();                 // tile 0
    __syncthreads();          // vmcnt(0) drain: tile 0 resident

    for (int s = 0; s < ksteps; ++s) {
        short8 fah[4], fal[4], fbh[4], fbl[4];
#pragma unroll
        for (int i = 0; i < 4; i++) {
            fah[i] = *(const short8*)&sAh[ar + i * 16 * 32];
            fal[i] = *(const short8*)&sAl[ar + i * 16 * 32];
            fbh[i] = *(const short8*)&sBh[br + i * 16 * 32];
            fbl[i] = *(const short8*)&sBl[br + i * 16 * 32];
        }
        __syncthreads();      // all waves done reading this tile (lgkm drained)

        if (s + 1 < ksteps) { // issue next tile's loads; they fly under the MFMAs
            gAh += 32; gAl += 32; gBh += 32; gBl += 32;
            STAGE8();
        }

        __builtin_amdgcn_s_setprio(1);
#pragma unroll
        for (int i = 0; i < 4; i++)
#pragma unroll
            for (int j = 0; j < 4; j++) {
                acc[i][j] = __builtin_amdgcn_mfma_f32_16x16x32_bf16(fah[i], fbh[j], acc[i][j], 0, 0, 0);
                acc[i][j] = __builtin_amdgcn_mfma_f32_16x16x32_bf16(fah[i], fbl[j], acc[i][j], 0, 0, 0);
                acc[i][j] = __builtin_amdgcn_mfma_f32_16x16x32_bf16(fal[i], fbh[j], acc[i][j], 0, 0, 0);
            }
        __builtin_amdgcn_s_setprio(0);
        __syncthreads();      // vmcnt(0): next tile resident
    }
#undef STAGE8

    // epilogue: C frag -> row = 4*(l>>4)+r, col = l&15  (m89-verified layout)
#pragma unroll
    for (int i = 0; i < 4; i++) {
        const int grow = bm + wr * 64 + i * 16 + (l >> 4) * 4;
#pragma unroll
        for (int j = 0; j < 4; j++) {
            const int gcol = bn + wc * 64 + j * 16 + (l & 15);
            f32x4 a = acc[i][j];
            if constexpr (EPI == 0) {
                const float bb = bias[gcol];
#pragma unroll
                for (int r = 0; r < 4; r++) {
                    int m = grow + r;
                    float x = gelu_tanh(a[r] + bb);
                    ushort h, lo; split2(x, h, lo);
                    int pr = (m < NROW) ? m : m - NROW;
                    int pc = ((m < NROW) ? 0 : E_) + gcol;
                    oPh[(size_t)pr * P2E_ + pc] = h;
                    oPl[(size_t)pr * P2E_ + pc] = lo;
                }
            } else if constexpr (EPI == 1) {
                float* o = outF + ((size_t)NROW * blockIdx.z + grow) * CD_ + gcol;
#pragma unroll
                for (int r = 0; r < 4; r++) o[(size_t)r * CD_] = a[r];
            } else {
#pragma unroll
                for (int r = 0; r < 4; r++) {
                    int m = grow + r;
                    outF[(size_t)m * NC_ + gcol] = (rn[m] - 2.0f * a[r]) + cn[gcol];
                }
            }
        }
    }
}

// elementwise fp32 -> (hi,lo) bf16 over TWO source tensors in one launch
__global__ void split2_k(const float* __restrict__ a, const float* __restrict__ b,
                         ushort* __restrict__ oh, ushort* __restrict__ ol, int n4each)
{
    int i = blockIdx.x * blockDim.x + threadIdx.x;
    int stride = gridDim.x * blockDim.x;
    for (; i < 2 * n4each; i += stride) {
        float4 v = (i < n4each) ? ((const float4*)a)[i] : ((const float4*)b)[i - n4each];
        ushort4 h, lo;
        split2(v.x, h.x, lo.x); split2(v.y, h.y, lo.y);
        split2(v.z, h.z, lo.z); split2(v.w, h.w, lo.w);
        ((ushort4*)oh)[i] = h;
        ((ushort4*)ol)[i] = lo;
    }
}

// elementwise fp32 -> (hi,lo) bf16 (single tensor)
__global__ void split_k(const float* __restrict__ in, ushort* __restrict__ oh,
                        ushort* __restrict__ ol, int n4)
{
    int i = blockIdx.x * blockDim.x + threadIdx.x;
    int stride = gridDim.x * blockDim.x;
    for (; i < n4; i += stride) {
        float4 v = ((const float4*)in)[i];
        ushort4 h, lo;
        split2(v.x, h.x, lo.x); split2(v.y, h.y, lo.y);
        split2(v.z, h.z, lo.z); split2(v.w, h.w, lo.w);
        ((ushort4*)oh)[i] = h;
        ((ushort4*)ol)[i] = lo;
    }
}

// transpose + split: in R x C fp32 -> out C x R (hi,lo) bf16
__global__ __launch_bounds__(1024)
void tsplit_k(const float* __restrict__ in, ushort* __restrict__ oh,
              ushort* __restrict__ ol, int R, int C)
{
    __shared__ float tile[32][33];
    int c0 = blockIdx.x * 32, r0 = blockIdx.y * 32;
    int tx = threadIdx.x, ty = threadIdx.y;
    tile[ty][tx] = in[(size_t)(r0 + ty) * C + c0 + tx];
    __syncthreads();
    float x = tile[tx][ty];
    ushort h, lo; split2(x, h, lo);
    size_t o = (size_t)(c0 + ty) * R + r0 + tx;
    oh[o] = h; ol[o] = lo;
}

// sum split-K partials + bias -> latent fp32, hi/lo bf16, row norms
__global__ __launch_bounds__(256)
void combine_k(const float* __restrict__ part, const float* __restrict__ bias,
               float* __restrict__ latent, ushort* __restrict__ lh,
               ushort* __restrict__ ll, float* __restrict__ rown)
{
    __shared__ float red[256];
    int row = blockIdx.x, t = threadIdx.x;
    float x = bias[t];
#pragma unroll
    for (int z = 0; z < SPLITK; z++) x += part[((size_t)z * NROW + row) * CD_ + t];
    latent[(size_t)row * CD_ + t] = x;
    ushort h, lo; split2(x, h, lo);
    lh[(size_t)row * CD_ + t] = h;
    ll[(size_t)row * CD_ + t] = lo;
    red[t] = x * x;
    __syncthreads();
    for (int st = 128; st > 0; st >>= 1) { if (t < st) red[t] += red[t + st]; __syncthreads(); }
    if (t == 0) rown[row] = red[0];
}

// ||row||^2 (256-col matrix) + zero hist[n] (grid == NC_ == hist size)
__global__ __launch_bounds__(256) void row_norms_zh(const float* __restrict__ X,
                                                    float* __restrict__ out,
                                                    int* __restrict__ hist)
{
    __shared__ float s[256];
    int n = blockIdx.x, t = threadIdx.x;
    float v = X[(size_t)n * 256 + t];
    s[t] = v * v;
    __syncthreads();
    for (int st = 128; st > 0; st >>= 1) {
        if (t < st) s[t] += s[t + st];
        __syncthreads();
    }
    if (t == 0) { out[n] = s[0]; hist[n] = 0; }
}

// One block per latent row. dists_enc holds dists on entry; overwritten with one-hot.
__global__ __launch_bounds__(256) void vq_kernel(
    const float* __restrict__ latent, const float* __restrict__ cb,
    float* __restrict__ dists_enc, float* __restrict__ out_q,
    float* __restrict__ out_idx, int* __restrict__ hist, float* __restrict__ lpart)
{
    __shared__ float sd[256];
    __shared__ int   si[256];
    const int n = blockIdx.x, tid = threadIdx.x;
    float* drow = dists_enc + (size_t)n * NC_;

    float best = INFINITY;
    int bidx = 0;
#pragma unroll
    for (int j = 0; j < NC_ / 256; j++) {
        int c = tid + j * 256;
        float d = drow[c];
        if (d < best) { best = d; bidx = c; }
    }
    sd[tid] = best; si[tid] = bidx;
    __syncthreads();
    for (int st = 128; st > 0; st >>= 1) {
        if (tid < st) {
            float d2 = sd[tid + st]; int i2 = si[tid + st];
            if (d2 < sd[tid] || (d2 == sd[tid] && i2 < si[tid])) { sd[tid] = d2; si[tid] = i2; }
        }
        __syncthreads();
    }
    const int bc = si[0];

#pragma unroll
    for (int j = 0; j < NC_ / 256; j++) {
        int c = tid + j * 256;
        drow[c] = (c == bc) ? 1.0f : 0.0f;
    }

    float lv = latent[(size_t)n * CD_ + tid];
    float q  = cb[(size_t)bc * CD_ + tid];
    out_q[(size_t)n * CD_ + tid] = lv + (q - lv);
    float diff = q - lv;
    __syncthreads();
    sd[tid] = diff * diff;
    __syncthreads();
    for (int st = 128; st > 0; st >>= 1) {
        if (tid < st) sd[tid] += sd[tid + st];
        __syncthreads();
    }
    if (tid == 0) {
        lpart[n] = sd[0];
        atomicAdd(&hist[bc], 1);
        out_idx[n] = (float)bc;
    }
}

__global__ __launch_bounds__(1024) void finalize_kernel(
    const float* __restrict__ lpart, const int* __restrict__ hist,
    float* __restrict__ out_loss, float* __restrict__ out_perp)
{
    __shared__ float s[1024];
    int t = threadIdx.x;
    float x = 0.0f;
    for (int i = t; i < NROW; i += 1024) x += lpart[i];
    s[t] = x;
    __syncthreads();
    for (int st = 512; st > 0; st >>= 1) {
        if (t < st) s[t] += s[t + st];
        __syncthreads();
    }
    float total = s[0];
    __syncthreads();
    float p = (float)hist[t] * (1.0f / NROW);
    s[t] = p * logf(p + 1e-10f);
    __syncthreads();
    for (int st = 512; st > 0; st >>= 1) {
        if (t < st) s[t] += s[t + st];
        __syncthreads();
    }
    if (t == 0) {
        *out_loss = BETA_ * (total / (float)((size_t)NROW * CD_));
        *out_perp = expf(-s[0]);
    }
}

extern "C" void kernel_launch(void* const* d_in, const int* in_sizes, int n_in,
                              void* d_out, int out_size, void* d_ws, size_t ws_size,
                              hipStream_t stream)
{
    const float* states      = (const float*)d_in[0];
    const float* next_states = (const float*)d_in[1];
    const float* W_s         = (const float*)d_in[2];
    const float* b_s         = (const float*)d_in[3];
    const float* W_p         = (const float*)d_in[4];
    const float* b_p         = (const float*)d_in[5];
    const float* codebook    = (const float*)d_in[6];

    float* out      = (float*)d_out;
    float* out_q    = out;
    float* out_loss = out + (size_t)NROW * CD_;
    float* out_perp = out_loss + 1;
    float* out_enc  = out_perp + 1;                  // dists scratch -> one-hot
    float* out_idx  = out_enc + (size_t)NROW * NC_;

    char* ws = (char*)d_ws;
    size_t off = 0;
    auto alloc = [&](size_t bytes) { void* p = ws + off; off += (bytes + 255) & ~255ull; return p; };

    ushort* A1h  = (ushort*)alloc((size_t)2 * NROW * D_ * 2);   // 32 MiB
    ushort* A1l  = (ushort*)alloc((size_t)2 * NROW * D_ * 2);   // 32 MiB
    ushort* WsTh = (ushort*)alloc((size_t)E_ * D_ * 2);
    ushort* WsTl = (ushort*)alloc((size_t)E_ * D_ * 2);
    ushort* WpTh = (ushort*)alloc((size_t)CD_ * P2E_ * 2);
    ushort* WpTl = (ushort*)alloc((size_t)CD_ * P2E_ * 2);
    ushort* cbh  = (ushort*)alloc((size_t)NC_ * CD_ * 2);
    ushort* cbl  = (ushort*)alloc((size_t)NC_ * CD_ * 2);
    ushort* Ph   = (ushort*)alloc((size_t)NROW * P2E_ * 2);     // 64 MiB
    ushort* Pl   = (ushort*)alloc((size_t)NROW * P2E_ * 2);
    ushort* lath = (ushort*)alloc((size_t)NROW * CD_ * 2);
    ushort* latl = (ushort*)alloc((size_t)NROW * CD_ * 2);
    float*  rown = (float*)alloc(NROW * 4);
    float*  cbn  = (float*)alloc(NC_ * 4);
    int*    hist = (int*)alloc(NC_ * 4);
    float*  lpart= (float*)alloc(NROW * 4);
    // aliases over dead regions (A1/WsT dead after GEMM1):
    float* lat_part = (float*)A1h;    // SPLITK*8192*256*4 = 32 MiB in A1h
    float* latent   = (float*)WsTh;   // 8 MiB over WsTh+WsTl

    // --- conversions ---
    split2_k<<<4096, 256, 0, stream>>>(states, next_states, A1h, A1l, NROW * D_ / 4);
    tsplit_k<<<dim3(E_ / 32, D_ / 32), dim3(32, 32), 0, stream>>>(W_s, WsTh, WsTl, D_, E_);
    tsplit_k<<<dim3(CD_ / 32, P2E_ / 32), dim3(32, 32), 0, stream>>>(W_p, WpTh, WpTl, P2E_, CD_);
    split_k<<<256, 256, 0, stream>>>(codebook, cbh, cbl, NC_ * CD_ / 4);
    row_norms_zh<<<NC_, 256, 0, stream>>>(codebook, cbn, hist);

    // --- GEMM1: P = gelu([states;next_states] @ W_s + b_s), concat layout, split hi/lo ---
    gemm_bf16x3<0><<<dim3(E_ / 128, 2 * NROW / 128), 256, 0, stream>>>(
        A1h, A1l, WsTh, WsTl, D_, D_ / 32, b_s, nullptr, Ph, Pl, nullptr, nullptr);

    // --- GEMM2: latent partials (split-K = 4) ---
    gemm_bf16x3<1><<<dim3(CD_ / 128, NROW / 128, SPLITK), 256, 0, stream>>>(
        Ph, Pl, WpTh, WpTl, P2E_, P2E_ / 32 / SPLITK, nullptr, lat_part, nullptr, nullptr,
        nullptr, nullptr);

    // --- combine: bias + fp32 latent + hi/lo + row norms ---
    combine_k<<<NROW, 256, 0, stream>>>(lat_part, b_p, latent, lath, latl, rown);

    // --- GEMM3: dists into encodings region ---
    gemm_bf16x3<2><<<dim3(NC_ / 128, NROW / 128), 256, 0, stream>>>(
        lath, latl, cbh, cbl, CD_, CD_ / 32, nullptr, out_enc, nullptr, nullptr,
        rown, cbn);

    // --- VQ: argmin, one-hot (in place), quantize_st, loss partials, histogram ---
    vq_kernel<<<NROW, 256, 0, stream>>>(latent, codebook, out_enc, out_q, out_idx, hist, lpart);

    // --- scalars ---
    finalize_kernel<<<1, 1024, 0, stream>>>(lpart, hist, out_loss, out_perp);
}